// Round 7
// baseline (93.251 us; speedup 1.0000x reference)
//
#include <hip/hip_runtime.h>

// Lennard-Jones per-edge energy + segment-sum — decomposed pipeline, no global atomics.
//
// R4-R6 evidence: monolithic K1 ~50us invariant under 3 different front-ends;
// cost cannot be localized from a fused kernel. R7 decomposes:
//   K1a: count edges per (bucket, block)            (ctr stream only)
//   s0:  bucket totals   s1: bucket bases (scan)    s2: per-bucket offset scan
//   K1c: compute energy + scatter to bucket-contiguous pairs via LDS cursors
//   K2:  per-bucket contiguous coalesced accumulate (grid nbucket x CH)
//   K3:  reduce CH chunk partials
// rocprof now decomposes the mystery cost per phase.
//
// Inputs: 0 sigma[16,16] 1 delta[16,16] 2 epsilon[16,16] (f32)
//         3 edge_len[E] 4 edge_cutoff[E] (f32)  5 edge_index[2,E] (int32)
//         6 atom_types[N] (int32)         Output: [N,1] f32.

#define THREADS 256
#define EPT     12            // edges per thread in count/scatter kernels
#define EPB     (THREADS*EPT) // 3072
#define BSHIFT  8
#define BSIZE   256
#define MAXBLK  2048
#define MAXBUCKET 512
#define SCAN_BBASE 512        // scan[] layout: [0..512) btot, [512..1025) bbase

__device__ __forceinline__ float lj_energy(float sig, float dlt, float eps,
                                           float len, float cut) {
    const float r  = sig / (len - dlt);
    const float r2 = r * r;
    const float x  = r2 * r2 * r2;               // (sig/(len-dlt))^6
    return 2.0f * eps * (x * x - x) * cut;
}

__device__ __forceinline__ void load_tables(const float* __restrict__ sigma,
                                            const float* __restrict__ delta,
                                            const float* __restrict__ epsilon,
                                            float* s_sig, float* s_dlt, float* s_eps,
                                            int t) {
    const int i  = t >> 4;
    const int j  = t & 15;
    const int lo = min(i, j);
    const int hi = max(i, j);
    const int src = lo * 16 + hi;          // sym = triu(p) + triu(p,1).T
    s_sig[t] = fmaxf(sigma[src],   0.0f);  // relu
    s_dlt[t] = fmaxf(delta[src],   0.0f);
    s_eps[t] = fmaxf(epsilon[src], 0.0f);
}

// ---------------- K1a: per-(bucket,block) edge counts -------------------------
__global__ __launch_bounds__(THREADS) void lj_count_kernel(
    const int* __restrict__ edge_index,      // [2,E]; row 0 = center
    uint32_t* __restrict__ offs,             // [nbucket][nblk] <- counts
    int n_edges, int nbucket, int nblk)
{
    __shared__ uint32_t hist[MAXBUCKET];
    const int t = threadIdx.x;
    hist[t] = 0u; hist[t + 256] = 0u;
    __syncthreads();

    const int blk = blockIdx.x;
    const int blkbase = blk * EPB;
    #pragma unroll
    for (int i = 0; i < EPT / 4; ++i) {
        const int g = blkbase + i * (THREADS * 4) + t * 4;
        if (g + 3 < n_edges) {
            const int4 ctr = *reinterpret_cast<const int4*>(edge_index + g);
            atomicAdd(&hist[ctr.x >> BSHIFT], 1u);
            atomicAdd(&hist[ctr.y >> BSHIFT], 1u);
            atomicAdd(&hist[ctr.z >> BSHIFT], 1u);
            atomicAdd(&hist[ctr.w >> BSHIFT], 1u);
        } else {
            for (int k = 0; k < 4; ++k) {
                const int e = g + k;
                if (e < n_edges) atomicAdd(&hist[edge_index[e] >> BSHIFT], 1u);
            }
        }
    }
    __syncthreads();
    for (int bb = t; bb < nbucket; bb += THREADS)
        offs[(size_t)bb * nblk + blk] = hist[bb];
}

// ---------------- s0: bucket totals ------------------------------------------
__global__ __launch_bounds__(THREADS) void lj_btot_kernel(
    const uint32_t* __restrict__ offs, uint32_t* __restrict__ scan, int nblk)
{
    __shared__ uint32_t red[THREADS];
    const int t = threadIdx.x;
    const int b = blockIdx.x;
    uint32_t s = 0;
    for (int i = t; i < nblk; i += THREADS) s += offs[(size_t)b * nblk + i];
    red[t] = s;
    __syncthreads();
    for (int off = THREADS / 2; off > 0; off >>= 1) {
        if (t < off) red[t] += red[t + off];
        __syncthreads();
    }
    if (t == 0) scan[b] = red[0];
}

// ---------------- s1: exclusive scan of bucket totals -> bases ----------------
__global__ __launch_bounds__(THREADS) void lj_bbase_kernel(
    uint32_t* __restrict__ scan, int nbucket)
{
    __shared__ uint32_t h[512];
    __shared__ uint32_t sc[THREADS];
    const int t = threadIdx.x;
    h[t]       = (t < nbucket)       ? scan[t]       : 0u;
    h[t + 256] = (t + 256 < nbucket) ? scan[t + 256] : 0u;
    __syncthreads();
    const uint32_t psum = h[2*t] + h[2*t + 1];
    sc[t] = psum;
    for (int off = 1; off < THREADS; off <<= 1) {
        __syncthreads();
        const uint32_t v = (t >= off) ? sc[t - off] : 0u;
        __syncthreads();
        sc[t] += v;
    }
    __syncthreads();
    const uint32_t excl = sc[t] - psum;
    scan[SCAN_BBASE + 2*t]     = excl;            // bbase[i], padded tail = total
    scan[SCAN_BBASE + 2*t + 1] = excl + h[2*t];
}

// ---------------- s2: per-bucket scan of counts + base add-back ---------------
__global__ __launch_bounds__(THREADS) void lj_offsets_kernel(
    uint32_t* __restrict__ offs, const uint32_t* __restrict__ scan, int nblk)
{
    __shared__ uint32_t row[MAXBLK];
    __shared__ uint32_t tp[THREADS];
    const int t = threadIdx.x;
    const int b = blockIdx.x;
    const uint32_t base = scan[SCAN_BBASE + b];

    for (int i = t; i < nblk; i += THREADS) row[i] = offs[(size_t)b * nblk + i];
    __syncthreads();

    const int C  = (nblk + THREADS - 1) / THREADS;
    const int lo = t * C;
    const int hi = min(nblk, lo + C);
    uint32_t s = 0;
    for (int i = lo; i < hi; ++i) s += row[i];
    tp[t] = s;
    for (int off = 1; off < THREADS; off <<= 1) {
        __syncthreads();
        const uint32_t v = (t >= off) ? tp[t - off] : 0u;
        __syncthreads();
        tp[t] += v;
    }
    __syncthreads();
    uint32_t run = base + tp[t] - s;
    for (int i = lo; i < hi; ++i) { const uint32_t c = row[i]; row[i] = run; run += c; }
    __syncthreads();
    for (int i = t; i < nblk; i += THREADS) offs[(size_t)b * nblk + i] = row[i];
}

// ---------------- K1c: energy + scatter to bucket-contiguous pairs ------------
__global__ __launch_bounds__(THREADS) void lj_scatter_kernel2(
    const float* __restrict__ sigma,
    const float* __restrict__ delta,
    const float* __restrict__ epsilon,
    const float* __restrict__ edge_len,
    const float* __restrict__ edge_cutoff,
    const int*  __restrict__ edge_index,
    const int*  __restrict__ atom_types,
    const uint32_t* __restrict__ offs,       // [nbucket][nblk] write cursors
    uint32_t* __restrict__ pairs,            // [n_edges] bucket-contiguous
    int n_edges, int nbucket, int nblk)
{
    __shared__ float s_sig[256], s_dlt[256], s_eps[256];
    __shared__ uint32_t cursor[MAXBUCKET];
    const int t = threadIdx.x;
    load_tables(sigma, delta, epsilon, s_sig, s_dlt, s_eps, t);

    const int blk = blockIdx.x;
    for (int bb = t; bb < nbucket; bb += THREADS)
        cursor[bb] = offs[(size_t)bb * nblk + blk];
    __syncthreads();

    const int blkbase = blk * EPB;
    #pragma unroll
    for (int i = 0; i < EPT / 4; ++i) {
        const int g = blkbase + i * (THREADS * 4) + t * 4;
        if (g + 3 < n_edges) {
            const int4   ctr = *reinterpret_cast<const int4*>(edge_index + g);
            const int4   oth = *reinterpret_cast<const int4*>(edge_index + n_edges + g);
            const float4 len = *reinterpret_cast<const float4*>(edge_len + g);
            const float4 cut = *reinterpret_cast<const float4*>(edge_cutoff + g);
            const int   c[4] = {ctr.x, ctr.y, ctr.z, ctr.w};
            const int   o[4] = {oth.x, oth.y, oth.z, oth.w};
            const float L[4] = {len.x, len.y, len.z, len.w};
            const float C_[4] = {cut.x, cut.y, cut.z, cut.w};
            #pragma unroll
            for (int k = 0; k < 4; ++k) {
                const int flat = (atom_types[c[k]] << 4) | atom_types[o[k]];
                const float e = lj_energy(s_sig[flat], s_dlt[flat], s_eps[flat],
                                          L[k], C_[k]);
                const uint32_t pk = (__float_as_uint(e) & ~255u) | (uint32_t)(c[k] & 255);
                const uint32_t r  = atomicAdd(&cursor[c[k] >> BSHIFT], 1u);
                pairs[r] = pk;
            }
        } else {
            for (int k = 0; k < 4; ++k) {
                const int e_idx = g + k;
                if (e_idx < n_edges) {
                    const int ci = edge_index[e_idx];
                    const int oi = edge_index[n_edges + e_idx];
                    const int flat = (atom_types[ci] << 4) | atom_types[oi];
                    const float e = lj_energy(s_sig[flat], s_dlt[flat], s_eps[flat],
                                              edge_len[e_idx], edge_cutoff[e_idx]);
                    const uint32_t pk = (__float_as_uint(e) & ~255u) | (uint32_t)(ci & 255);
                    const uint32_t r  = atomicAdd(&cursor[ci >> BSHIFT], 1u);
                    pairs[r] = pk;
                }
            }
        }
    }
}

// ---------------- K2: contiguous per-(bucket,chunk) accumulate ----------------
__global__ __launch_bounds__(THREADS) void lj_accum_kernel(
    const uint32_t* __restrict__ pairs,
    const uint32_t* __restrict__ scan,       // bbase at +SCAN_BBASE
    float* __restrict__ dst,
    long long limit)
{
    __shared__ float acc[4][BSIZE];
    const int t  = threadIdx.x;
    const int b  = blockIdx.x;
    const int c  = blockIdx.y;
    const int CH = gridDim.y;

    const uint32_t lo  = scan[SCAN_BBASE + b];
    const uint32_t hi  = scan[SCAN_BBASE + b + 1];
    const uint32_t len = hi - lo;
    const uint32_t clen = (len + CH - 1) / CH;
    const uint32_t s0 = lo + c * clen;
    const uint32_t s1 = min(hi, s0 + clen);

    #pragma unroll
    for (int w = 0; w < 4; ++w) acc[w][t] = 0.0f;
    __syncthreads();

    const int wave = t >> 6;
    for (uint32_t i = s0 + t; i < s1; i += THREADS) {
        const uint32_t p = pairs[i];
        atomicAdd(&acc[wave][p & 255u], __uint_as_float(p & ~255u));
    }
    __syncthreads();

    const long long idx = ((long long)b * CH + c) * BSIZE + t;
    if (idx < limit)
        dst[idx] = acc[0][t] + acc[1][t] + acc[2][t] + acc[3][t];
}

// ---------------- K3: reduce CH chunk-partials -> out -------------------------
__global__ __launch_bounds__(THREADS) void lj_reduce_kernel(
    const float* __restrict__ partial, float* __restrict__ out,
    int n_nodes, int CH)
{
    const int n = blockIdx.x * THREADS + threadIdx.x;
    if (n < n_nodes) {
        const int b = n >> BSHIFT;
        const int i = n & (BSIZE - 1);
        float s = 0.0f;
        for (int c = 0; c < CH; ++c)
            s += partial[(((size_t)b * CH + c) << BSHIFT) + i];
        out[n] = s;
    }
}

// ---------------- fallback: direct device-scope atomics -----------------------
__global__ __launch_bounds__(THREADS) void lj_scatter_direct(
    const float* __restrict__ sigma,
    const float* __restrict__ delta,
    const float* __restrict__ epsilon,
    const float* __restrict__ edge_len,
    const float* __restrict__ edge_cutoff,
    const int*  __restrict__ edge_index,
    const int*  __restrict__ atom_types,
    float* __restrict__ out,
    int n_edges)
{
    __shared__ float s_sig[256], s_dlt[256], s_eps[256];
    const int t = threadIdx.x;
    load_tables(sigma, delta, epsilon, s_sig, s_dlt, s_eps, t);
    __syncthreads();

    const int base = (blockIdx.x * THREADS + t) * 4;
    if (base >= n_edges) return;
    const int lim = min(base + 4, n_edges);
    for (int e = base; e < lim; ++e) {
        const int ci = edge_index[e];
        const int oi = edge_index[n_edges + e];
        const int flat = (atom_types[ci] << 4) | atom_types[oi];
        const float en = lj_energy(s_sig[flat], s_dlt[flat], s_eps[flat],
                                   edge_len[e], edge_cutoff[e]);
        atomicAdd(out + ci, en);
    }
}

static inline size_t align16(size_t x) { return (x + 15) & ~(size_t)15; }

extern "C" void kernel_launch(void* const* d_in, const int* in_sizes, int n_in,
                              void* d_out, int out_size, void* d_ws, size_t ws_size,
                              hipStream_t stream) {
    const float* sigma       = (const float*)d_in[0];
    const float* delta       = (const float*)d_in[1];
    const float* epsilon     = (const float*)d_in[2];
    const float* edge_len    = (const float*)d_in[3];
    const float* edge_cutoff = (const float*)d_in[4];
    const int*   edge_index  = (const int*)d_in[5];
    const int*   atom_types  = (const int*)d_in[6];
    float*       out         = (float*)d_out;

    const int n_edges = in_sizes[3];
    const int n_nodes = in_sizes[6];

    const int nblk    = (n_edges + EPB - 1) / EPB;
    const int nbucket = (n_nodes + BSIZE - 1) / BSIZE;

    const size_t offs_bytes  = align16((size_t)nbucket * nblk * sizeof(uint32_t));
    const size_t scan_bytes  = align16(1032 * sizeof(uint32_t));
    const size_t pairs_bytes = align16((size_t)n_edges * sizeof(uint32_t));
    const size_t need_base   = offs_bytes + scan_bytes + pairs_bytes;

    if (nbucket <= MAXBUCKET && nblk <= MAXBLK && ws_size >= need_base) {
        uint32_t* offs  = (uint32_t*)d_ws;
        uint32_t* scan  = (uint32_t*)((char*)d_ws + offs_bytes);
        uint32_t* pairs = (uint32_t*)((char*)d_ws + offs_bytes + scan_bytes);

        int CH = 1;
        for (int tryCH = 8; tryCH >= 2; tryCH >>= 1) {
            const size_t part = (size_t)nbucket * tryCH * BSIZE * sizeof(float);
            if (ws_size >= need_base + part) { CH = tryCH; break; }
        }

        lj_count_kernel<<<nblk, THREADS, 0, stream>>>(
            edge_index, offs, n_edges, nbucket, nblk);
        lj_btot_kernel<<<nbucket, THREADS, 0, stream>>>(offs, scan, nblk);
        lj_bbase_kernel<<<1, THREADS, 0, stream>>>(scan, nbucket);
        lj_offsets_kernel<<<nbucket, THREADS, 0, stream>>>(offs, scan, nblk);
        lj_scatter_kernel2<<<nblk, THREADS, 0, stream>>>(
            sigma, delta, epsilon, edge_len, edge_cutoff,
            edge_index, atom_types, offs, pairs, n_edges, nbucket, nblk);

        if (CH == 1) {
            lj_accum_kernel<<<dim3(nbucket, 1), THREADS, 0, stream>>>(
                pairs, scan, out, (long long)n_nodes);
        } else {
            float* partial = (float*)((char*)d_ws + need_base);
            const long long plimit = (long long)nbucket * CH * BSIZE;
            lj_accum_kernel<<<dim3(nbucket, CH), THREADS, 0, stream>>>(
                pairs, scan, partial, plimit);
            const int rgrid = (n_nodes + THREADS - 1) / THREADS;
            lj_reduce_kernel<<<rgrid, THREADS, 0, stream>>>(
                partial, out, n_nodes, CH);
        }
    } else {
        hipMemsetAsync(d_out, 0, (size_t)out_size * sizeof(float), stream);
        const int grid = (n_edges + THREADS * 4 - 1) / (THREADS * 4);
        lj_scatter_direct<<<grid, THREADS, 0, stream>>>(
            sigma, delta, epsilon, edge_len, edge_cutoff,
            edge_index, atom_types, out, n_edges);
    }
}

// Round 8
// 90.025 us; speedup vs baseline: 1.0358x; 1.0358x over previous
//
#include <hip/hip_runtime.h>

// Lennard-Jones per-edge energy + segment-sum — decomposed, no global atomics.
//
// R7 ablation: count/scans/accum ≈ 8us total; ALL cost sits in the scatter
// (gathers at low MLP + random 4B stores). R8:
//   K1a' lj_count_flat: per-(bucket,block) counts AND per-edge type-pair byte
//        (the only kernel doing random gathers; tiny body for MLP)
//   s0/s1/s2: scans (unchanged, cheap)
//   K1c  lj_scatter3: energy from flat byte, LDS counting-sort, run-coalesced
//        copy-out to bucket-contiguous pairs (no gathers, no random 4B stores)
//   K2   lj_accum: contiguous per-(bucket,chunk) accumulate (cheap)  + K3 reduce
//
// Inputs: 0 sigma[16,16] 1 delta[16,16] 2 epsilon[16,16] (f32)
//         3 edge_len[E] 4 edge_cutoff[E] (f32)  5 edge_index[2,E] (int32)
//         6 atom_types[N] (int32)         Output: [N,1] f32.

#define THREADS 256
#define EPT     12
#define EPB     (THREADS*EPT)   // 3072
#define BSHIFT  8
#define BSIZE   256
#define MAXBLK  2048
#define MAXBUCKET 512
#define SCAN_BBASE 512          // scan[]: [0..512) btot, [512..1025) bbase

__device__ __forceinline__ float lj_energy(float sig, float dlt, float eps,
                                           float len, float cut) {
    const float r  = sig / (len - dlt);
    const float r2 = r * r;
    const float x  = r2 * r2 * r2;               // (sig/(len-dlt))^6
    return 2.0f * eps * (x * x - x) * cut;
}

__device__ __forceinline__ void load_tables(const float* __restrict__ sigma,
                                            const float* __restrict__ delta,
                                            const float* __restrict__ epsilon,
                                            float* s_sig, float* s_dlt, float* s_eps,
                                            int t) {
    const int i  = t >> 4;
    const int j  = t & 15;
    const int lo = min(i, j);
    const int hi = max(i, j);
    const int src = lo * 16 + hi;          // sym = triu(p) + triu(p,1).T
    s_sig[t] = fmaxf(sigma[src],   0.0f);  // relu
    s_dlt[t] = fmaxf(delta[src],   0.0f);
    s_eps[t] = fmaxf(epsilon[src], 0.0f);
}

// ---------------- K1a': counts + per-edge type-pair byte ----------------------
__global__ __launch_bounds__(THREADS) void lj_count_flat(
    const int* __restrict__ edge_index,      // [2,E]
    const int* __restrict__ atom_types,      // [N]
    uint32_t* __restrict__ offs,             // [nbucket][nblk] <- counts
    uint8_t*  __restrict__ flat,             // [E] (tc<<4)|to
    int n_edges, int nbucket, int nblk)
{
    __shared__ uint32_t hist[MAXBUCKET];
    const int t = threadIdx.x;
    hist[t] = 0u; hist[t + 256] = 0u;
    __syncthreads();

    const int blk = blockIdx.x;
    const int blkbase = blk * EPB;
    #pragma unroll
    for (int i = 0; i < EPT / 4; ++i) {
        const int g = blkbase + i * (THREADS * 4) + t * 4;
        if (g + 3 < n_edges) {
            const int4 ctr = *reinterpret_cast<const int4*>(edge_index + g);
            const int4 oth = *reinterpret_cast<const int4*>(edge_index + n_edges + g);
            atomicAdd(&hist[ctr.x >> BSHIFT], 1u);
            atomicAdd(&hist[ctr.y >> BSHIFT], 1u);
            atomicAdd(&hist[ctr.z >> BSHIFT], 1u);
            atomicAdd(&hist[ctr.w >> BSHIFT], 1u);
            const int tc0 = atom_types[ctr.x], tc1 = atom_types[ctr.y];
            const int tc2 = atom_types[ctr.z], tc3 = atom_types[ctr.w];
            const int to0 = atom_types[oth.x], to1 = atom_types[oth.y];
            const int to2 = atom_types[oth.z], to3 = atom_types[oth.w];
            const uint32_t f =  (uint32_t)((tc0 << 4) | to0)
                             | ((uint32_t)((tc1 << 4) | to1) << 8)
                             | ((uint32_t)((tc2 << 4) | to2) << 16)
                             | ((uint32_t)((tc3 << 4) | to3) << 24);
            *reinterpret_cast<uint32_t*>(flat + g) = f;
        } else {
            for (int k = 0; k < 4; ++k) {
                const int e = g + k;
                if (e < n_edges) {
                    const int ci = edge_index[e];
                    const int oi = edge_index[n_edges + e];
                    atomicAdd(&hist[ci >> BSHIFT], 1u);
                    flat[e] = (uint8_t)((atom_types[ci] << 4) | atom_types[oi]);
                }
            }
        }
    }
    __syncthreads();
    for (int bb = t; bb < nbucket; bb += THREADS)
        offs[(size_t)bb * nblk + blk] = hist[bb];
}

// ---------------- s0: bucket totals ------------------------------------------
__global__ __launch_bounds__(THREADS) void lj_btot_kernel(
    const uint32_t* __restrict__ offs, uint32_t* __restrict__ scan, int nblk)
{
    __shared__ uint32_t red[THREADS];
    const int t = threadIdx.x;
    const int b = blockIdx.x;
    uint32_t s = 0;
    for (int i = t; i < nblk; i += THREADS) s += offs[(size_t)b * nblk + i];
    red[t] = s;
    __syncthreads();
    for (int off = THREADS / 2; off > 0; off >>= 1) {
        if (t < off) red[t] += red[t + off];
        __syncthreads();
    }
    if (t == 0) scan[b] = red[0];
}

// ---------------- s1: exclusive scan of bucket totals -> bases ----------------
__global__ __launch_bounds__(THREADS) void lj_bbase_kernel(
    uint32_t* __restrict__ scan, int nbucket)
{
    __shared__ uint32_t h[512];
    __shared__ uint32_t sc[THREADS];
    const int t = threadIdx.x;
    h[t]       = (t < nbucket)       ? scan[t]       : 0u;
    h[t + 256] = (t + 256 < nbucket) ? scan[t + 256] : 0u;
    __syncthreads();
    const uint32_t psum = h[2*t] + h[2*t + 1];
    sc[t] = psum;
    for (int off = 1; off < THREADS; off <<= 1) {
        __syncthreads();
        const uint32_t v = (t >= off) ? sc[t - off] : 0u;
        __syncthreads();
        sc[t] += v;
    }
    __syncthreads();
    const uint32_t excl = sc[t] - psum;
    scan[SCAN_BBASE + 2*t]     = excl;
    scan[SCAN_BBASE + 2*t + 1] = excl + h[2*t];
}

// ---------------- s2: per-bucket scan of counts + base add-back ---------------
__global__ __launch_bounds__(THREADS) void lj_offsets_kernel(
    uint32_t* __restrict__ offs, const uint32_t* __restrict__ scan, int nblk)
{
    __shared__ uint32_t row[MAXBLK];
    __shared__ uint32_t tp[THREADS];
    const int t = threadIdx.x;
    const int b = blockIdx.x;
    const uint32_t base = scan[SCAN_BBASE + b];

    for (int i = t; i < nblk; i += THREADS) row[i] = offs[(size_t)b * nblk + i];
    __syncthreads();

    const int C  = (nblk + THREADS - 1) / THREADS;
    const int lo = t * C;
    const int hi = min(nblk, lo + C);
    uint32_t s = 0;
    for (int i = lo; i < hi; ++i) s += row[i];
    tp[t] = s;
    for (int off = 1; off < THREADS; off <<= 1) {
        __syncthreads();
        const uint32_t v = (t >= off) ? tp[t - off] : 0u;
        __syncthreads();
        tp[t] += v;
    }
    __syncthreads();
    uint32_t run = base + tp[t] - s;
    for (int i = lo; i < hi; ++i) { const uint32_t c = row[i]; row[i] = run; run += c; }
    __syncthreads();
    for (int i = t; i < nblk; i += THREADS) offs[(size_t)b * nblk + i] = row[i];
}

// ---------------- K1c: energy + LDS sort + run-coalesced copy-out -------------
template<bool USE_FLAT>
__device__ __forceinline__ void scatter_body(
    const float* __restrict__ sigma,
    const float* __restrict__ delta,
    const float* __restrict__ epsilon,
    const float* __restrict__ edge_len,
    const float* __restrict__ edge_cutoff,
    const int*  __restrict__ edge_index,
    const int*  __restrict__ atom_types,
    const uint8_t* __restrict__ flat,
    const uint32_t* __restrict__ offs,       // [nbucket][nblk] global positions
    uint32_t* __restrict__ pairs,            // [E] bucket-contiguous
    int n_edges, int nbucket, int nblk)
{
    __shared__ float s_sig[256], s_dlt[256], s_eps[256];
    __shared__ uint32_t hist[MAXBUCKET];      // counts -> cursor
    __shared__ uint32_t lbase[MAXBUCKET];     // local exclusive base
    __shared__ uint32_t goffs[MAXBUCKET];     // global base for this block
    __shared__ uint32_t stage[EPB];
    __shared__ unsigned short stageb[EPB];

    const int t = threadIdx.x;
    const int blk = blockIdx.x;
    load_tables(sigma, delta, epsilon, s_sig, s_dlt, s_eps, t);
    hist[t] = 0u; hist[t + 256] = 0u;
    for (int bb = t; bb < nbucket; bb += THREADS)
        goffs[bb] = offs[(size_t)bb * nblk + blk];

    const int blkbase = blk * EPB;

    // load this thread's 12 edges
    int   c_[EPT];
    float L_[EPT], C_[EPT];
    int   f_[EPT];                 // flat byte (USE_FLAT) or other-node id
    #pragma unroll
    for (int i = 0; i < EPT / 4; ++i) {
        const int g = blkbase + i * (THREADS * 4) + t * 4;
        if (g + 3 < n_edges) {
            const int4   ctr = *reinterpret_cast<const int4*>(edge_index + g);
            const float4 len = *reinterpret_cast<const float4*>(edge_len + g);
            const float4 cut = *reinterpret_cast<const float4*>(edge_cutoff + g);
            c_[i*4+0] = ctr.x; c_[i*4+1] = ctr.y; c_[i*4+2] = ctr.z; c_[i*4+3] = ctr.w;
            L_[i*4+0] = len.x; L_[i*4+1] = len.y; L_[i*4+2] = len.z; L_[i*4+3] = len.w;
            C_[i*4+0] = cut.x; C_[i*4+1] = cut.y; C_[i*4+2] = cut.z; C_[i*4+3] = cut.w;
            if (USE_FLAT) {
                const uint32_t f = *reinterpret_cast<const uint32_t*>(flat + g);
                f_[i*4+0] = (int)(f & 255u);
                f_[i*4+1] = (int)((f >> 8) & 255u);
                f_[i*4+2] = (int)((f >> 16) & 255u);
                f_[i*4+3] = (int)((f >> 24) & 255u);
            } else {
                const int4 oth = *reinterpret_cast<const int4*>(edge_index + n_edges + g);
                f_[i*4+0] = oth.x; f_[i*4+1] = oth.y; f_[i*4+2] = oth.z; f_[i*4+3] = oth.w;
            }
        } else {
            for (int k = 0; k < 4; ++k) {
                const int e = g + k;
                const bool v = (e < n_edges);
                c_[i*4+k] = v ? edge_index[e] : -1;
                L_[i*4+k] = v ? edge_len[e] : 1.0f;
                C_[i*4+k] = v ? edge_cutoff[e] : 0.0f;
                if (USE_FLAT) f_[i*4+k] = v ? (int)flat[e] : 0;
                else          f_[i*4+k] = v ? edge_index[n_edges + e] : 0;
            }
        }
    }
    __syncthreads();   // tables + hist + goffs ready

    // histogram
    int bk[EPT];
    #pragma unroll
    for (int j = 0; j < EPT; ++j) {
        if (c_[j] >= 0) { bk[j] = c_[j] >> BSHIFT; atomicAdd(&hist[bk[j]], 1u); }
        else bk[j] = -1;
    }
    __syncthreads();

    // wave-0 in-register exclusive scan -> lbase and cursor(hist)
    if (t < 64) {
        uint32_t v[8]; uint32_t s = 0;
        #pragma unroll
        for (int k = 0; k < 8; ++k) {
            const uint32_t tmp = hist[t * 8 + k];
            v[k] = s; s += tmp;
        }
        uint32_t inc = s;
        #pragma unroll
        for (int off = 1; off < 64; off <<= 1) {
            const uint32_t u = __shfl_up(inc, off, 64);
            if (t >= off) inc += u;
        }
        const uint32_t lane_excl = inc - s;
        #pragma unroll
        for (int k = 0; k < 8; ++k) {
            const uint32_t e = lane_excl + v[k];
            lbase[t * 8 + k] = e;
            hist[t * 8 + k]  = e;       // cursor
        }
    }
    __syncthreads();

    // compute energy + rank-scatter into LDS stage
    #pragma unroll
    for (int j = 0; j < EPT; ++j) {
        if (bk[j] >= 0) {
            int fl;
            if (USE_FLAT) fl = f_[j];
            else          fl = (atom_types[c_[j]] << 4) | atom_types[f_[j]];
            const float e = lj_energy(s_sig[fl], s_dlt[fl], s_eps[fl], L_[j], C_[j]);
            const uint32_t pk = (__float_as_uint(e) & ~255u) | (uint32_t)(c_[j] & 255);
            const uint32_t r  = atomicAdd(&hist[bk[j]], 1u);
            stage[r]  = pk;
            stageb[r] = (unsigned short)bk[j];
        }
    }
    __syncthreads();

    // run-coalesced copy-out: consecutive stage idx in a bucket -> consecutive dst
    const int nval = min(EPB, n_edges - blkbase);
    for (int i = t; i < nval; i += THREADS) {
        const int bb = stageb[i];
        pairs[goffs[bb] + (uint32_t)i - lbase[bb]] = stage[i];
    }
}

__global__ __launch_bounds__(THREADS) void lj_scatter3_flat(
    const float* sigma, const float* delta, const float* epsilon,
    const float* edge_len, const float* edge_cutoff,
    const int* edge_index, const int* atom_types, const uint8_t* flat,
    const uint32_t* offs, uint32_t* pairs, int n_edges, int nbucket, int nblk)
{
    scatter_body<true>(sigma, delta, epsilon, edge_len, edge_cutoff,
                       edge_index, atom_types, flat, offs, pairs,
                       n_edges, nbucket, nblk);
}

__global__ __launch_bounds__(THREADS) void lj_scatter3_gather(
    const float* sigma, const float* delta, const float* epsilon,
    const float* edge_len, const float* edge_cutoff,
    const int* edge_index, const int* atom_types,
    const uint32_t* offs, uint32_t* pairs, int n_edges, int nbucket, int nblk)
{
    scatter_body<false>(sigma, delta, epsilon, edge_len, edge_cutoff,
                        edge_index, atom_types, nullptr, offs, pairs,
                        n_edges, nbucket, nblk);
}

// ---------------- K2: contiguous per-(bucket,chunk) accumulate ----------------
__global__ __launch_bounds__(THREADS) void lj_accum_kernel(
    const uint32_t* __restrict__ pairs,
    const uint32_t* __restrict__ scan,       // bbase at +SCAN_BBASE
    float* __restrict__ dst,
    long long limit)
{
    __shared__ float acc[4][BSIZE];
    const int t  = threadIdx.x;
    const int b  = blockIdx.x;
    const int c  = blockIdx.y;
    const int CH = gridDim.y;

    const uint32_t lo  = scan[SCAN_BBASE + b];
    const uint32_t hi  = scan[SCAN_BBASE + b + 1];
    const uint32_t len = hi - lo;
    const uint32_t clen = (len + CH - 1) / CH;
    const uint32_t s0 = lo + c * clen;
    const uint32_t s1 = min(hi, s0 + clen);

    #pragma unroll
    for (int w = 0; w < 4; ++w) acc[w][t] = 0.0f;
    __syncthreads();

    const int wave = t >> 6;
    for (uint32_t i = s0 + t; i < s1; i += THREADS) {
        const uint32_t p = pairs[i];
        atomicAdd(&acc[wave][p & 255u], __uint_as_float(p & ~255u));
    }
    __syncthreads();

    const long long idx = ((long long)b * CH + c) * BSIZE + t;
    if (idx < limit)
        dst[idx] = acc[0][t] + acc[1][t] + acc[2][t] + acc[3][t];
}

// ---------------- K3: reduce CH chunk-partials -> out -------------------------
__global__ __launch_bounds__(THREADS) void lj_reduce_kernel(
    const float* __restrict__ partial, float* __restrict__ out,
    int n_nodes, int CH)
{
    const int n = blockIdx.x * THREADS + threadIdx.x;
    if (n < n_nodes) {
        const int b = n >> BSHIFT;
        const int i = n & (BSIZE - 1);
        float s = 0.0f;
        for (int c = 0; c < CH; ++c)
            s += partial[(((size_t)b * CH + c) << BSHIFT) + i];
        out[n] = s;
    }
}

// ---------------- fallback: direct device-scope atomics -----------------------
__global__ __launch_bounds__(THREADS) void lj_scatter_direct(
    const float* __restrict__ sigma,
    const float* __restrict__ delta,
    const float* __restrict__ epsilon,
    const float* __restrict__ edge_len,
    const float* __restrict__ edge_cutoff,
    const int*  __restrict__ edge_index,
    const int*  __restrict__ atom_types,
    float* __restrict__ out,
    int n_edges)
{
    __shared__ float s_sig[256], s_dlt[256], s_eps[256];
    const int t = threadIdx.x;
    load_tables(sigma, delta, epsilon, s_sig, s_dlt, s_eps, t);
    __syncthreads();

    const int base = (blockIdx.x * THREADS + t) * 4;
    if (base >= n_edges) return;
    const int lim = min(base + 4, n_edges);
    for (int e = base; e < lim; ++e) {
        const int ci = edge_index[e];
        const int oi = edge_index[n_edges + e];
        const int flat = (atom_types[ci] << 4) | atom_types[oi];
        const float en = lj_energy(s_sig[flat], s_dlt[flat], s_eps[flat],
                                   edge_len[e], edge_cutoff[e]);
        atomicAdd(out + ci, en);
    }
}

static inline size_t align16(size_t x) { return (x + 15) & ~(size_t)15; }

extern "C" void kernel_launch(void* const* d_in, const int* in_sizes, int n_in,
                              void* d_out, int out_size, void* d_ws, size_t ws_size,
                              hipStream_t stream) {
    const float* sigma       = (const float*)d_in[0];
    const float* delta       = (const float*)d_in[1];
    const float* epsilon     = (const float*)d_in[2];
    const float* edge_len    = (const float*)d_in[3];
    const float* edge_cutoff = (const float*)d_in[4];
    const int*   edge_index  = (const int*)d_in[5];
    const int*   atom_types  = (const int*)d_in[6];
    float*       out         = (float*)d_out;

    const int n_edges = in_sizes[3];
    const int n_nodes = in_sizes[6];

    const int nblk    = (n_edges + EPB - 1) / EPB;
    const int nbucket = (n_nodes + BSIZE - 1) / BSIZE;

    const size_t offs_bytes  = align16((size_t)nbucket * nblk * sizeof(uint32_t));
    const size_t scan_bytes  = align16(1032 * sizeof(uint32_t));
    const size_t pairs_bytes = align16((size_t)n_edges * sizeof(uint32_t));
    const size_t need_core   = offs_bytes + scan_bytes + pairs_bytes;
    const size_t flat_bytes  = align16((size_t)n_edges);

    if (nbucket <= MAXBUCKET && nblk <= MAXBLK && ws_size >= need_core) {
        uint32_t* offs  = (uint32_t*)d_ws;
        uint32_t* scan  = (uint32_t*)((char*)d_ws + offs_bytes);
        uint32_t* pairs = (uint32_t*)((char*)d_ws + offs_bytes + scan_bytes);

        const bool use_flat = (ws_size >= need_core + flat_bytes);
        uint8_t* flat = use_flat ? (uint8_t*)((char*)d_ws + need_core) : nullptr;
        const size_t used = need_core + (use_flat ? flat_bytes : 0);

        // pick CH + partials placement: tail space, else overlay dead offs
        int CH = 1;
        float* partial = nullptr;
        for (int tryCH = 8; tryCH >= 2; tryCH >>= 1) {
            const size_t part = (size_t)nbucket * tryCH * BSIZE * sizeof(float);
            if (ws_size >= used + part) {
                CH = tryCH; partial = (float*)((char*)d_ws + used); break;
            }
            if (part <= offs_bytes) {          // offs is dead after scatter
                CH = tryCH; partial = (float*)d_ws; break;
            }
        }

        if (use_flat) {
            lj_count_flat<<<nblk, THREADS, 0, stream>>>(
                edge_index, atom_types, offs, flat, n_edges, nbucket, nblk);
        } else {
            // counts only (reuse count_flat shape without flat: use direct kernel)
            lj_count_flat<<<nblk, THREADS, 0, stream>>>(
                edge_index, atom_types, offs, (uint8_t*)pairs /*scratch*/, 
                n_edges, nbucket, nblk);   // flat scratch = pairs (overwritten later)
        }
        lj_btot_kernel<<<nbucket, THREADS, 0, stream>>>(offs, scan, nblk);
        lj_bbase_kernel<<<1, THREADS, 0, stream>>>(scan, nbucket);
        lj_offsets_kernel<<<nbucket, THREADS, 0, stream>>>(offs, scan, nblk);

        if (use_flat) {
            lj_scatter3_flat<<<nblk, THREADS, 0, stream>>>(
                sigma, delta, epsilon, edge_len, edge_cutoff,
                edge_index, atom_types, flat, offs, pairs, n_edges, nbucket, nblk);
        } else {
            lj_scatter3_gather<<<nblk, THREADS, 0, stream>>>(
                sigma, delta, epsilon, edge_len, edge_cutoff,
                edge_index, atom_types, offs, pairs, n_edges, nbucket, nblk);
        }

        if (CH == 1) {
            lj_accum_kernel<<<dim3(nbucket, 1), THREADS, 0, stream>>>(
                pairs, scan, out, (long long)n_nodes);
        } else {
            const long long plimit = (long long)nbucket * CH * BSIZE;
            lj_accum_kernel<<<dim3(nbucket, CH), THREADS, 0, stream>>>(
                pairs, scan, partial, plimit);
            const int rgrid = (n_nodes + THREADS - 1) / THREADS;
            lj_reduce_kernel<<<rgrid, THREADS, 0, stream>>>(
                partial, out, n_nodes, CH);
        }
    } else {
        hipMemsetAsync(d_out, 0, (size_t)out_size * sizeof(float), stream);
        const int grid = (n_edges + THREADS * 4 - 1) / (THREADS * 4);
        lj_scatter_direct<<<grid, THREADS, 0, stream>>>(
            sigma, delta, epsilon, edge_len, edge_cutoff,
            edge_index, atom_types, out, n_edges);
    }
}